// Round 1
// baseline (318.706 us; speedup 1.0000x reference)
//
#include <hip/hip_runtime.h>

// AgreementRouting: capsule dynamic routing, fused single kernel.
// Shapes fixed by harness: u[B=32][G=8][S=1152][O=10][D=16] f32, b_param[G][1][S][O] f32.
#define NB 32
#define NG 8
#define NS 1152
#define NO 10
#define ND 16
#define EPSV 1e-8f

#define THREADS 512            // 8 waves; 4 lanes per s-row -> 128 rows/step, 9 steps
#define NWAVES (THREADS / 64)
#define GRPS (THREADS / 4)
#define NSTEPS (NS / GRPS)

__global__ __launch_bounds__(THREADS)
void AgreementRouting_72988674228343_kernel(const float* __restrict__ u,
                                            const float* __restrict__ b_param,
                                            const int* __restrict__ n_iter_p,
                                            float* __restrict__ out) {
    __shared__ float  b_lds[NS * NO];        // 45 KB: full logits tile for this (b,g)
    __shared__ float4 sred[NWAVES][NO][4];   // per-wave partial s-sums
    __shared__ float4 v_lds[NO][4];          // squashed v broadcast

    const int tid  = threadIdx.x;
    const int blk  = blockIdx.x;             // = b*NG + g
    const int g    = blk & (NG - 1);
    const int bb   = blk >> 3;
    const int wave = tid >> 6;
    const int lane = tid & 63;
    const int d4   = tid & 3;                // which float4 chunk of D this lane owns
    const int grp  = tid >> 2;               // s-row group within block (0..127)

    const int n_iter = n_iter_p[0];

    // init logits from b_param[g,0,s,o] (broadcast over B)
    const float* bp = b_param + (size_t)g * (NS * NO);
    for (int i = tid; i < NS * NO; i += THREADS) b_lds[i] = bp[i];

    const float4* ub = (const float4*)u + (size_t)blk * (NS * NO * ND / 4);

    float4 v[NO];                            // lane's d-chunk of v[o]
    __syncthreads();

    for (int r = 0; r < n_iter; ++r) {
        float4 sacc[NO];
#pragma unroll
        for (int o = 0; o < NO; ++o) sacc[o] = make_float4(0.f, 0.f, 0.f, 0.f);

        for (int step = 0; step < NSTEPS; ++step) {
            const int s = step * GRPS + grp;
            const float4* row = ub + (size_t)s * (NO * 4) + d4;
            float4 uu[NO];
#pragma unroll
            for (int o = 0; o < NO; ++o) uu[o] = row[o * 4];   // 10 independent 16B loads

            float bnew[NO];
            if (r > 0) {
                // agreement a[o] = sum_d u[s,o,d] * v[o,d]; reduce over 4 lanes
                float p[NO];
#pragma unroll
                for (int o = 0; o < NO; ++o)
                    p[o] = uu[o].x * v[o].x + uu[o].y * v[o].y +
                           uu[o].z * v[o].z + uu[o].w * v[o].w;
#pragma unroll
                for (int o = 0; o < NO; ++o) {
                    p[o] += __shfl_xor(p[o], 1);
                    p[o] += __shfl_xor(p[o], 2);
                    bnew[o] = b_lds[s * NO + o] + p[o];
                }
                // write back updated logits (each lane writes o with o%4==d4)
#pragma unroll
                for (int o = 0; o < NO; ++o)
                    if ((o & 3) == d4) b_lds[s * NO + o] = bnew[o];
            } else {
#pragma unroll
                for (int o = 0; o < NO; ++o) bnew[o] = b_lds[s * NO + o];
            }

            // in-register softmax over O (redundant per lane; we're BW-bound)
            float m = bnew[0];
#pragma unroll
            for (int o = 1; o < NO; ++o) m = fmaxf(m, bnew[o]);
            float e[NO]; float ssum = 0.f;
#pragma unroll
            for (int o = 0; o < NO; ++o) { e[o] = __expf(bnew[o] - m); ssum += e[o]; }
            const float inv = 1.f / ssum;
#pragma unroll
            for (int o = 0; o < NO; ++o) {
                const float c = e[o] * inv;
                sacc[o].x += c * uu[o].x;
                sacc[o].y += c * uu[o].y;
                sacc[o].z += c * uu[o].z;
                sacc[o].w += c * uu[o].w;
            }
        }

        // reduce sacc across the 16 groups of each wave (keep d4 identity: masks 4..32)
#pragma unroll
        for (int o = 0; o < NO; ++o) {
#pragma unroll
            for (int mask = 4; mask <= 32; mask <<= 1) {
                sacc[o].x += __shfl_xor(sacc[o].x, mask);
                sacc[o].y += __shfl_xor(sacc[o].y, mask);
                sacc[o].z += __shfl_xor(sacc[o].z, mask);
                sacc[o].w += __shfl_xor(sacc[o].w, mask);
            }
        }
        if (lane < 4) {
#pragma unroll
            for (int o = 0; o < NO; ++o) sred[wave][o][lane] = sacc[o];
        }
        __syncthreads();

        if (tid < NO * 4) {                  // 40 threads: (o, d-chunk)
            const int o = tid >> 2, dd = tid & 3;
            float4 sv = sred[0][o][dd];
#pragma unroll
            for (int w = 1; w < NWAVES; ++w) {
                float4 t = sred[w][o][dd];
                sv.x += t.x; sv.y += t.y; sv.z += t.z; sv.w += t.w;
            }
            // squash: v = s * (|s|^2/(1+|s|^2)) / (|s| + eps)
            float q = sv.x * sv.x + sv.y * sv.y + sv.z * sv.z + sv.w * sv.w;
            q += __shfl_xor(q, 1);
            q += __shfl_xor(q, 2);
            const float len = sqrtf(q);
            const float f = (q / (1.f + q)) / (len + EPSV);
            const float4 vv = make_float4(sv.x * f, sv.y * f, sv.z * f, sv.w * f);
            v_lds[o][dd] = vv;
            if (r == n_iter - 1) {
                float* op = out + (size_t)bb * (NO * ND) + o * ND + dd * 4;
                atomicAdd(op + 0, vv.x);
                atomicAdd(op + 1, vv.y);
                atomicAdd(op + 2, vv.z);
                atomicAdd(op + 3, vv.w);
            }
        }
        __syncthreads();
#pragma unroll
        for (int o = 0; o < NO; ++o) v[o] = v_lds[o][d4];
        // (next iteration's sred/v_lds writes are fenced by its own first __syncthreads)
    }
}

extern "C" void kernel_launch(void* const* d_in, const int* in_sizes, int n_in,
                              void* d_out, int out_size, void* d_ws, size_t ws_size,
                              hipStream_t stream) {
    const float* u   = (const float*)d_in[0];
    const float* bp  = (const float*)d_in[1];
    const int*   nit = (const int*)d_in[2];
    float* out = (float*)d_out;

    // out is re-poisoned before every timed launch; zero it (memset node is capturable)
    hipMemsetAsync(out, 0, (size_t)out_size * sizeof(float), stream);

    AgreementRouting_72988674228343_kernel<<<dim3(NB * NG), dim3(THREADS), 0, stream>>>(
        u, bp, nit, out);
}